// Round 12
// baseline (142.054 us; speedup 1.0000x reference)
//
#include <hip/hip_runtime.h>
#include <hip/hip_bf16.h>

#define Bn 4096
#define Dk 1024
#define EPSF 1e-7f
#define GEMM_BLOCKS 512   // (4096/256) * (4096/128)

typedef float f32x4 __attribute__((ext_vector_type(4)));
typedef long long2_t __attribute__((ext_vector_type(2)));

__device__ __forceinline__ void async_copy16(const void* g, void* l) {
    __builtin_amdgcn_global_load_lds((__attribute__((address_space(1))) void*)(uintptr_t)g,
                                     (__attribute__((address_space(3))) void*)l, 16, 0, 0);
}

// -------- Kernel 1: L2-normalize -> fp8 e4m3 (x8 prescale), K-INTERLEAVED layout ----
// Granule q (16 B) of each 64-B K-group holds k-bytes [8q..8q+7] and [32+8q..32+8q+7];
// both operands share the permutation so dot products are unchanged, and one ds_read_b128
// yields a lane's two k-step fragments. Also zeroes rowsum/colsum and the completion counter.
__global__ __launch_bounds__(256)
void nrm_kernel(const float4* __restrict__ left, const float4* __restrict__ right,
                unsigned char* __restrict__ lnb8, unsigned char* __restrict__ rnb8,
                float* __restrict__ diag, float* __restrict__ rowsum,
                float* __restrict__ colsum, unsigned* __restrict__ counter)
{
    const int row = blockIdx.x;
    const int t = threadIdx.x;
    const int idx = row * (Dk / 4) + t;
    const float4 l = left[idx];
    const float4 r = right[idx];
    float sl = l.x * l.x + l.y * l.y + l.z * l.z + l.w * l.w;
    float sr = r.x * r.x + r.y * r.y + r.z * r.z + r.w * r.w;
    float slr = l.x * r.x + l.y * r.y + l.z * r.z + l.w * r.w;
    #pragma unroll
    for (int off = 1; off < 64; off <<= 1) {
        sl += __shfl_xor(sl, off);
        sr += __shfl_xor(sr, off);
        slr += __shfl_xor(slr, off);
    }
    __shared__ float red[3][4];
    const int wave = t >> 6, lane = t & 63;
    if (lane == 0) { red[0][wave] = sl; red[1][wave] = sr; red[2][wave] = slr; }
    __syncthreads();
    sl = red[0][0] + red[0][1] + red[0][2] + red[0][3];
    sr = red[1][0] + red[1][1] + red[1][2] + red[1][3];
    const float invl = 1.0f / sqrtf(fmaxf(sl, EPSF));
    const float invr = 1.0f / sqrtf(fmaxf(sr, EPSF));
    const float sL = 8.0f * invl;
    const float sR = 8.0f * invr;
    int pkL = __builtin_amdgcn_cvt_pk_fp8_f32(l.x * sL, l.y * sL, 0, false);
    pkL = __builtin_amdgcn_cvt_pk_fp8_f32(l.z * sL, l.w * sL, pkL, true);
    int pkR = __builtin_amdgcn_cvt_pk_fp8_f32(r.x * sR, r.y * sR, 0, false);
    pkR = __builtin_amdgcn_cvt_pk_fp8_f32(r.z * sR, r.w * sR, pkR, true);
    const int k0 = 4 * t;
    const int g = k0 >> 6;
    const int kl = k0 & 63;
    const int dst = row * Dk + (g << 6) + (((kl & 31) >> 3) << 4) + ((kl >> 5) << 3) + (kl & 7);
    *(unsigned*)(lnb8 + dst) = (unsigned)pkL;
    *(unsigned*)(rnb8 + dst) = (unsigned)pkR;
    if (t == 0) {
        const float d = red[2][0] + red[2][1] + red[2][2] + red[2][3];
        diag[row] = d * invl * invr;
        rowsum[row] = 0.f;
        colsum[row] = 0.f;
        if (row == 0) *counter = 0u;   // completion counter for the fused loss tail
    }
}

// -------- Kernel 2: S = ln . rn^T, fp8 16x16x32 MFMA, 128x256 tile + FUSED LOSS TAIL ----
// R10's gemm verbatim (empirical best of the family: vmcnt-pipelined ping-pong LDS,
// K-interleaved b128 fragments, 128x256 tile, wave tile 64x128). After the epilogue's
// atomics, blocks increment a device-scope counter; the LAST block performs the final
// loss reduction (formerly a third kernel) — saves one dispatch.
__global__ __launch_bounds__(256, 2)
void gemm_sm_kernel(const unsigned char* __restrict__ lnb8,
                    const unsigned char* __restrict__ rnb8,
                    const float* __restrict__ temp,
                    float* __restrict__ rowsum, float* __restrict__ colsum,
                    const float* __restrict__ diag, unsigned* __restrict__ counter,
                    float* __restrict__ out)
{
    __shared__ __align__(16) unsigned char As[2][128 * 64];
    __shared__ __align__(16) unsigned char Bs[2][256 * 64];

    const int tid = threadIdx.x;
    const int wave = tid >> 6;
    const int lane = tid & 63;
    const int bm0 = blockIdx.y * 128;
    const int bn0 = blockIdx.x * 256;

    // ---- staging: wave stages A rows [32w,32w+32) (2 insts) and B rows [64w,64w+64) (4 insts)
    const int srow = lane >> 2;
    const int sj = lane & 3;
    int goffA[2], lofsA[2];
    #pragma unroll
    for (int i = 0; i < 2; ++i) {
        const int rloc = wave * 32 + i * 16 + srow;
        goffA[i] = rloc * Dk + 16 * (sj ^ ((rloc >> 1) & 3));
        lofsA[i] = (wave * 32 + i * 16) * 64;
    }
    int goffB[4], lofsB[4];
    #pragma unroll
    for (int i = 0; i < 4; ++i) {
        const int rloc = wave * 64 + i * 16 + srow;
        goffB[i] = rloc * Dk + 16 * (sj ^ ((rloc >> 1) & 3));
        lofsB[i] = (wave * 64 + i * 16) * 64;
    }
    const unsigned char* baseA = lnb8 + (size_t)bm0 * Dk;
    const unsigned char* baseB = rnb8 + (size_t)bn0 * Dk;

    // ---- compute-side: wave tile 64x128; wm=(wave&1)*64 (M), wn=(wave>>1)*128 (N)
    const int wm = (wave & 1) * 64;
    const int wn = (wave >> 1) * 128;
    const int quad = lane >> 4;
    const int r16 = lane & 15;
    const int skey = (r16 >> 1) & 3;
    const int gq = 16 * (quad ^ skey);
    int aoff[4], boff[8];
    #pragma unroll
    for (int i = 0; i < 4; ++i)
        aoff[i] = (wm + i * 16 + r16) * 64 + gq;
    #pragma unroll
    for (int i = 0; i < 8; ++i)
        boff[i] = (wn + i * 16 + r16) * 64 + gq;

    f32x4 acc[4][8];
    #pragma unroll
    for (int i = 0; i < 4; ++i)
        #pragma unroll
        for (int j = 0; j < 8; ++j)
            acc[i][j] = (f32x4){0.f, 0.f, 0.f, 0.f};

    // prologue: stage tile 0 into buffer 0
    #pragma unroll
    for (int i = 0; i < 2; ++i) async_copy16(baseA + goffA[i], &As[0][lofsA[i]]);
    #pragma unroll
    for (int i = 0; i < 4; ++i) async_copy16(baseB + goffB[i], &Bs[0][lofsB[i]]);

    #pragma unroll 2
    for (int it = 0; it < 16; ++it) {
        const int cur = it & 1;
        const int nxt = cur ^ 1;
        const int knext = ((it + 1) & 15) * 64;   // wraps on last iter (dummy reload)
        #pragma unroll
        for (int i = 0; i < 2; ++i) async_copy16(baseA + goffA[i] + knext, &As[nxt][lofsA[i]]);
        #pragma unroll
        for (int i = 0; i < 4; ++i) async_copy16(baseB + goffB[i] + knext, &Bs[nxt][lofsB[i]]);
        // wait only the PREVIOUS tile's 6 loads; prefetch stays in flight
        asm volatile("s_waitcnt vmcnt(6)\n\ts_barrier" ::: "memory");
        long2_t af01[4], bf01[8];
        #pragma unroll
        for (int i = 0; i < 4; ++i) af01[i] = *(const long2_t*)(&As[cur][aoff[i]]);
        #pragma unroll
        for (int i = 0; i < 8; ++i) bf01[i] = *(const long2_t*)(&Bs[cur][boff[i]]);
        #pragma unroll
        for (int mi = 0; mi < 4; ++mi)
            #pragma unroll
            for (int ni = 0; ni < 8; ++ni)
                acc[mi][ni] = __builtin_amdgcn_mfma_f32_16x16x32_fp8_fp8(
                    af01[mi].x, bf01[ni].x, acc[mi][ni], 0, 0, 0);
        #pragma unroll
        for (int mi = 0; mi < 4; ++mi)
            #pragma unroll
            for (int ni = 0; ni < 8; ++ni)
                acc[mi][ni] = __builtin_amdgcn_mfma_f32_16x16x32_fp8_fp8(
                    af01[mi].y, bf01[ni].y, acc[mi][ni], 0, 0, 0);
        // execution-only barrier: everyone done reading `cur` before it is restaged
        asm volatile("s_barrier" ::: "memory");
    }

    // epilogue: undo the 8x8 prescale (2^-6, exact), then p = exp(scale*s - scale)
    const float scale = __expf(temp[0]);
    const float dq = 0.015625f * scale;  // 2^-6 * scale
    #pragma unroll
    for (int mi = 0; mi < 4; ++mi)
        #pragma unroll
        for (int ni = 0; ni < 8; ++ni)
            #pragma unroll
            for (int r = 0; r < 4; ++r)
                acc[mi][ni][r] = __expf(dq * acc[mi][ni][r] - scale);

    // C/D layout: col = lane&15, row = quad*4 + reg
    #pragma unroll
    for (int mi = 0; mi < 4; ++mi) {
        #pragma unroll
        for (int r = 0; r < 4; ++r) {
            float v = 0.f;
            #pragma unroll
            for (int ni = 0; ni < 8; ++ni) v += acc[mi][ni][r];
            v += __shfl_xor(v, 1);
            v += __shfl_xor(v, 2);
            v += __shfl_xor(v, 4);
            v += __shfl_xor(v, 8);
            if (r16 == 0)
                atomicAdd(&rowsum[bm0 + wm + mi * 16 + quad * 4 + r], v);
        }
    }
    #pragma unroll
    for (int ni = 0; ni < 8; ++ni) {
        float v = 0.f;
        #pragma unroll
        for (int mi = 0; mi < 4; ++mi)
            #pragma unroll
            for (int r = 0; r < 4; ++r)
                v += acc[mi][ni][r];
        v += __shfl_xor(v, 16);
        v += __shfl_xor(v, 32);
        if (quad == 0)
            atomicAdd(&colsum[bn0 + wn + ni * 16 + r16], v);
    }

    // ---- fused loss tail: last block to finish computes the scalar loss ----
    __threadfence();                      // release: my rowsum/colsum atomics device-visible
    __shared__ unsigned done;
    if (tid == 0) done = atomicAdd(counter, 1u);
    __syncthreads();
    if (done == GEMM_BLOCKS - 1) {
        __threadfence();                  // acquire: all other blocks' atomics visible
        float dL = 0.f, dR = 0.f;
        for (int i = tid; i < Bn; i += 256) {
            const float e = __expf(scale * (diag[i] - 1.0f));
            dL += e * __builtin_amdgcn_rcpf(rowsum[i]);
            dR += e * __builtin_amdgcn_rcpf(colsum[i]);
        }
        #pragma unroll
        for (int off = 1; off < 64; off <<= 1) {
            dL += __shfl_xor(dL, off);
            dR += __shfl_xor(dR, off);
        }
        __shared__ float rd[2][4];
        if (lane == 0) { rd[0][wave] = dL; rd[1][wave] = dR; }
        __syncthreads();
        if (tid == 0) {
            dL = rd[0][0] + rd[0][1] + rd[0][2] + rd[0][3];
            dR = rd[1][0] + rd[1][1] + rd[1][2] + rd[1][3];
            const float logeps = logf(EPSF);
            const float log1m = logf(1.0f - EPSF);
            const float lossL = -(dL * log1m + ((float)Bn - dL) * logeps);
            const float lossR = -(dR * log1m + ((float)Bn - dR) * logeps);
            out[0] = (lossL + lossR) * 0.5f / (float)Bn;
        }
    }
}

extern "C" void kernel_launch(void* const* d_in, const int* in_sizes, int n_in,
                              void* d_out, int out_size, void* d_ws, size_t ws_size,
                              hipStream_t stream) {
    (void)in_sizes; (void)n_in; (void)out_size; (void)ws_size;
    const float* left = (const float*)d_in[0];
    const float* right = (const float*)d_in[1];
    const float* temp = (const float*)d_in[2];

    char* ws = (char*)d_ws;
    unsigned char* lnb8 = (unsigned char*)ws;                       // 4 MiB
    unsigned char* rnb8 = (unsigned char*)(ws + (size_t)Bn * Dk);   // 4 MiB
    float* diag = (float*)(ws + 2 * (size_t)Bn * Dk);
    float* rowsum = diag + Bn;
    float* colsum = rowsum + Bn;
    unsigned* counter = (unsigned*)(colsum + Bn);

    nrm_kernel<<<Bn, 256, 0, stream>>>((const float4*)left, (const float4*)right,
                                       lnb8, rnb8, diag, rowsum, colsum, counter);
    dim3 g2(Bn / 256, Bn / 128);
    gemm_sm_kernel<<<g2, 256, 0, stream>>>(lnb8, rnb8, temp, rowsum, colsum,
                                           diag, counter, (float*)d_out);
}

// Round 13
// 112.513 us; speedup vs baseline: 1.2626x; 1.2626x over previous
//
#include <hip/hip_runtime.h>
#include <hip/hip_bf16.h>

#define Bn 4096
#define Dk 1024
#define EPSF 1e-7f

typedef float f32x4 __attribute__((ext_vector_type(4)));
typedef long long2_t __attribute__((ext_vector_type(2)));

__device__ __forceinline__ void async_copy16(const void* g, void* l) {
    __builtin_amdgcn_global_load_lds((__attribute__((address_space(1))) void*)(uintptr_t)g,
                                     (__attribute__((address_space(3))) void*)l, 16, 0, 0);
}

// -------- Kernel 1: L2-normalize -> fp8 e4m3 (x8 prescale), K-INTERLEAVED layout ----
// Granule q (16 B) of each 64-B K-group holds k-bytes [8q..8q+7] and [32+8q..32+8q+7];
// both operands share the permutation so dot products are unchanged, and one ds_read_b128
// yields a lane's two k-step fragments.
__global__ __launch_bounds__(256)
void nrm_kernel(const float4* __restrict__ left, const float4* __restrict__ right,
                unsigned char* __restrict__ lnb8, unsigned char* __restrict__ rnb8,
                float* __restrict__ diag, float* __restrict__ rowsum,
                float* __restrict__ colsum)
{
    const int row = blockIdx.x;
    const int t = threadIdx.x;
    const int idx = row * (Dk / 4) + t;
    const float4 l = left[idx];
    const float4 r = right[idx];
    float sl = l.x * l.x + l.y * l.y + l.z * l.z + l.w * l.w;
    float sr = r.x * r.x + r.y * r.y + r.z * r.z + r.w * r.w;
    float slr = l.x * r.x + l.y * r.y + l.z * r.z + l.w * r.w;
    #pragma unroll
    for (int off = 1; off < 64; off <<= 1) {
        sl += __shfl_xor(sl, off);
        sr += __shfl_xor(sr, off);
        slr += __shfl_xor(slr, off);
    }
    __shared__ float red[3][4];
    const int wave = t >> 6, lane = t & 63;
    if (lane == 0) { red[0][wave] = sl; red[1][wave] = sr; red[2][wave] = slr; }
    __syncthreads();
    sl = red[0][0] + red[0][1] + red[0][2] + red[0][3];
    sr = red[1][0] + red[1][1] + red[1][2] + red[1][3];
    const float invl = 1.0f / sqrtf(fmaxf(sl, EPSF));
    const float invr = 1.0f / sqrtf(fmaxf(sr, EPSF));
    const float sL = 8.0f * invl;
    const float sR = 8.0f * invr;
    int pkL = __builtin_amdgcn_cvt_pk_fp8_f32(l.x * sL, l.y * sL, 0, false);
    pkL = __builtin_amdgcn_cvt_pk_fp8_f32(l.z * sL, l.w * sL, pkL, true);
    int pkR = __builtin_amdgcn_cvt_pk_fp8_f32(r.x * sR, r.y * sR, 0, false);
    pkR = __builtin_amdgcn_cvt_pk_fp8_f32(r.z * sR, r.w * sR, pkR, true);
    const int k0 = 4 * t;
    const int g = k0 >> 6;
    const int kl = k0 & 63;
    const int dst = row * Dk + (g << 6) + (((kl & 31) >> 3) << 4) + ((kl >> 5) << 3) + (kl & 7);
    *(unsigned*)(lnb8 + dst) = (unsigned)pkL;
    *(unsigned*)(rnb8 + dst) = (unsigned)pkR;
    if (t == 0) {
        const float d = red[2][0] + red[2][1] + red[2][2] + red[2][3];
        diag[row] = d * invl * invr;
        rowsum[row] = 0.f;
        colsum[row] = 0.f;
    }
}

// -------- Kernel 2: S = ln . rn^T, fp8 16x16x32 MFMA, 128x256 tile (session optimum) ----
// Best measured config (R10): ping-pong LDS, raw "s_waitcnt vmcnt(6); s_barrier" (prefetch
// stays in flight across the barrier), execution-only post-barrier, K-interleaved
// ds_read_b128 fragments, block 128x256 / wave tile 64x128, acc in AGPRs.
// R12's fused loss tail REGRESSED (agent-scope fence + register pressure: 37->71 us) —
// keep the loss as a separate tiny kernel.
__global__ __launch_bounds__(256, 2)
void gemm_sm_kernel(const unsigned char* __restrict__ lnb8,
                    const unsigned char* __restrict__ rnb8,
                    const float* __restrict__ temp,
                    float* __restrict__ rowsum, float* __restrict__ colsum)
{
    __shared__ __align__(16) unsigned char As[2][128 * 64];
    __shared__ __align__(16) unsigned char Bs[2][256 * 64];

    const int tid = threadIdx.x;
    const int wave = tid >> 6;
    const int lane = tid & 63;
    const int bm0 = blockIdx.y * 128;
    const int bn0 = blockIdx.x * 256;

    // ---- staging: wave stages A rows [32w,32w+32) (2 insts) and B rows [64w,64w+64) (4 insts)
    const int srow = lane >> 2;
    const int sj = lane & 3;
    int goffA[2], lofsA[2];
    #pragma unroll
    for (int i = 0; i < 2; ++i) {
        const int rloc = wave * 32 + i * 16 + srow;
        goffA[i] = rloc * Dk + 16 * (sj ^ ((rloc >> 1) & 3));
        lofsA[i] = (wave * 32 + i * 16) * 64;
    }
    int goffB[4], lofsB[4];
    #pragma unroll
    for (int i = 0; i < 4; ++i) {
        const int rloc = wave * 64 + i * 16 + srow;
        goffB[i] = rloc * Dk + 16 * (sj ^ ((rloc >> 1) & 3));
        lofsB[i] = (wave * 64 + i * 16) * 64;
    }
    const unsigned char* baseA = lnb8 + (size_t)bm0 * Dk;
    const unsigned char* baseB = rnb8 + (size_t)bn0 * Dk;

    // ---- compute-side: wave tile 64x128; wm=(wave&1)*64 (M), wn=(wave>>1)*128 (N)
    const int wm = (wave & 1) * 64;
    const int wn = (wave >> 1) * 128;
    const int quad = lane >> 4;
    const int r16 = lane & 15;
    const int skey = (r16 >> 1) & 3;
    const int gq = 16 * (quad ^ skey);
    int aoff[4], boff[8];
    #pragma unroll
    for (int i = 0; i < 4; ++i)
        aoff[i] = (wm + i * 16 + r16) * 64 + gq;
    #pragma unroll
    for (int i = 0; i < 8; ++i)
        boff[i] = (wn + i * 16 + r16) * 64 + gq;

    f32x4 acc[4][8];
    #pragma unroll
    for (int i = 0; i < 4; ++i)
        #pragma unroll
        for (int j = 0; j < 8; ++j)
            acc[i][j] = (f32x4){0.f, 0.f, 0.f, 0.f};

    // prologue: stage tile 0 into buffer 0
    #pragma unroll
    for (int i = 0; i < 2; ++i) async_copy16(baseA + goffA[i], &As[0][lofsA[i]]);
    #pragma unroll
    for (int i = 0; i < 4; ++i) async_copy16(baseB + goffB[i], &Bs[0][lofsB[i]]);

    #pragma unroll 2
    for (int it = 0; it < 16; ++it) {
        const int cur = it & 1;
        const int nxt = cur ^ 1;
        const int knext = ((it + 1) & 15) * 64;   // wraps on last iter (dummy reload)
        #pragma unroll
        for (int i = 0; i < 2; ++i) async_copy16(baseA + goffA[i] + knext, &As[nxt][lofsA[i]]);
        #pragma unroll
        for (int i = 0; i < 4; ++i) async_copy16(baseB + goffB[i] + knext, &Bs[nxt][lofsB[i]]);
        // wait only the PREVIOUS tile's 6 loads; prefetch stays in flight
        asm volatile("s_waitcnt vmcnt(6)\n\ts_barrier" ::: "memory");
        long2_t af01[4], bf01[8];
        #pragma unroll
        for (int i = 0; i < 4; ++i) af01[i] = *(const long2_t*)(&As[cur][aoff[i]]);
        #pragma unroll
        for (int i = 0; i < 8; ++i) bf01[i] = *(const long2_t*)(&Bs[cur][boff[i]]);
        #pragma unroll
        for (int mi = 0; mi < 4; ++mi)
            #pragma unroll
            for (int ni = 0; ni < 8; ++ni)
                acc[mi][ni] = __builtin_amdgcn_mfma_f32_16x16x32_fp8_fp8(
                    af01[mi].x, bf01[ni].x, acc[mi][ni], 0, 0, 0);
        #pragma unroll
        for (int mi = 0; mi < 4; ++mi)
            #pragma unroll
            for (int ni = 0; ni < 8; ++ni)
                acc[mi][ni] = __builtin_amdgcn_mfma_f32_16x16x32_fp8_fp8(
                    af01[mi].y, bf01[ni].y, acc[mi][ni], 0, 0, 0);
        // execution-only barrier: everyone done reading `cur` before it is restaged
        asm volatile("s_barrier" ::: "memory");
    }

    // epilogue: undo the 8x8 prescale (2^-6, exact), then p = exp(scale*s - scale)
    const float scale = __expf(temp[0]);
    const float dq = 0.015625f * scale;  // 2^-6 * scale
    #pragma unroll
    for (int mi = 0; mi < 4; ++mi)
        #pragma unroll
        for (int ni = 0; ni < 8; ++ni)
            #pragma unroll
            for (int r = 0; r < 4; ++r)
                acc[mi][ni][r] = __expf(dq * acc[mi][ni][r] - scale);

    // C/D layout: col = lane&15, row = quad*4 + reg
    #pragma unroll
    for (int mi = 0; mi < 4; ++mi) {
        #pragma unroll
        for (int r = 0; r < 4; ++r) {
            float v = 0.f;
            #pragma unroll
            for (int ni = 0; ni < 8; ++ni) v += acc[mi][ni][r];
            v += __shfl_xor(v, 1);
            v += __shfl_xor(v, 2);
            v += __shfl_xor(v, 4);
            v += __shfl_xor(v, 8);
            if (r16 == 0)
                atomicAdd(&rowsum[bm0 + wm + mi * 16 + quad * 4 + r], v);
        }
    }
    #pragma unroll
    for (int ni = 0; ni < 8; ++ni) {
        float v = 0.f;
        #pragma unroll
        for (int mi = 0; mi < 4; ++mi)
            #pragma unroll
            for (int r = 0; r < 4; ++r)
                v += acc[mi][ni][r];
        v += __shfl_xor(v, 16);
        v += __shfl_xor(v, 32);
        if (quad == 0)
            atomicAdd(&colsum[bn0 + wn + ni * 16 + r16], v);
    }
}

// -------- Kernel 3: final scalar loss --------
__global__ __launch_bounds__(256)
void loss_kernel(const float* __restrict__ diag, const float* __restrict__ rowsum,
                 const float* __restrict__ colsum, const float* __restrict__ temp,
                 float* __restrict__ out)
{
    const int t = threadIdx.x;
    const float scale = __expf(temp[0]);
    float dL = 0.f, dR = 0.f;
    for (int i = t; i < Bn; i += 256) {
        const float e = __expf(scale * (diag[i] - 1.0f));
        dL += e * __builtin_amdgcn_rcpf(rowsum[i]);
        dR += e * __builtin_amdgcn_rcpf(colsum[i]);
    }
    #pragma unroll
    for (int off = 1; off < 64; off <<= 1) {
        dL += __shfl_xor(dL, off);
        dR += __shfl_xor(dR, off);
    }
    __shared__ float rd[2][4];
    const int wave = t >> 6, lane = t & 63;
    if (lane == 0) { rd[0][wave] = dL; rd[1][wave] = dR; }
    __syncthreads();
    if (t == 0) {
        dL = rd[0][0] + rd[0][1] + rd[0][2] + rd[0][3];
        dR = rd[1][0] + rd[1][1] + rd[1][2] + rd[1][3];
        const float logeps = logf(EPSF);
        const float log1m = logf(1.0f - EPSF);
        const float lossL = -(dL * log1m + ((float)Bn - dL) * logeps);
        const float lossR = -(dR * log1m + ((float)Bn - dR) * logeps);
        out[0] = (lossL + lossR) * 0.5f / (float)Bn;
    }
}

extern "C" void kernel_launch(void* const* d_in, const int* in_sizes, int n_in,
                              void* d_out, int out_size, void* d_ws, size_t ws_size,
                              hipStream_t stream) {
    (void)in_sizes; (void)n_in; (void)out_size; (void)ws_size;
    const float* left = (const float*)d_in[0];
    const float* right = (const float*)d_in[1];
    const float* temp = (const float*)d_in[2];

    char* ws = (char*)d_ws;
    unsigned char* lnb8 = (unsigned char*)ws;                       // 4 MiB
    unsigned char* rnb8 = (unsigned char*)(ws + (size_t)Bn * Dk);   // 4 MiB
    float* diag = (float*)(ws + 2 * (size_t)Bn * Dk);
    float* rowsum = diag + Bn;
    float* colsum = rowsum + Bn;

    nrm_kernel<<<Bn, 256, 0, stream>>>((const float4*)left, (const float4*)right,
                                       lnb8, rnb8, diag, rowsum, colsum);
    dim3 g2(Bn / 256, Bn / 128);
    gemm_sm_kernel<<<g2, 256, 0, stream>>>(lnb8, rnb8, temp, rowsum, colsum);
    loss_kernel<<<1, 256, 0, stream>>>(diag, rowsum, colsum, temp, (float*)d_out);
}